// Round 5
// baseline (134.496 us; speedup 1.0000x reference)
//
#include <hip/hip_runtime.h>
#include <hip/hip_bf16.h>

// TripletLoss: fused E·E^T + masked row min/max reduction. B=8192, D=256.
// dist = sqrt(2-2*sim) monotone decreasing in sim =>
//   dist_ap = dist(min sim over positives), dist_an = dist(max sim over negatives).
//
// R9: NO LDS, NO BARRIERS. Ebf is 4 MB -> L2/L3-resident (guide: staging cache-fit
// data is pure overhead). B-fragments are read directly from global: lane (quad,r16)
// reads col n0+nt*16+r16, k-chunk quad*8 — each 16-lane group covers 16 full 64B
// lines (coalesced); the block's 4 waves share the same 16KB tile per iter -> L1
// serves the redundancy. Waves free-run and de-phase (latency hiding without
// occupancy). k-loop is depth-1 software-pipelined; the next tile's k=0 fragment is
// prefetched at k=7 so its latency hides under the fold. Register budget == R5
// (zero headroom exists: R8 proved the 256-reg cliff).

#define BDIM 8192
#define DDIM 256

typedef short bf16x8 __attribute__((ext_vector_type(8)));
typedef float f32x4  __attribute__((ext_vector_type(4)));
typedef unsigned short u16;

static __device__ __forceinline__ bf16x8 ld_frag(const u16* p) {
    return *reinterpret_cast<const bf16x8*>(p);
}

static __device__ __forceinline__ u16 f2bf(float f) {
    union { float f; unsigned int u; } x; x.f = f;
    unsigned int u = x.u;
    unsigned int r = u + 0x7fffu + ((u >> 16) & 1u);  // RNE
    return (u16)(r >> 16);
}

// ---- kernel 1: fp32 -> bf16 convert + init reduction arrays ----
__global__ __launch_bounds__(256) void cvt_init_kernel(const float* __restrict__ in,
                                                       u16* __restrict__ out,
                                                       int* __restrict__ minpos,
                                                       int* __restrict__ maxneg) {
    int i = blockIdx.x * 256 + threadIdx.x;          // 524288 threads, 4 elems each
    const float4 v = reinterpret_cast<const float4*>(in)[i];
    ushort4 o;
    o.x = f2bf(v.x); o.y = f2bf(v.y); o.z = f2bf(v.z); o.w = f2bf(v.w);
    reinterpret_cast<ushort4*>(out)[i] = o;
    if (i < BDIM) {
        minpos[i] = 0x7f800000;                      // +inf  (min over positives of sim+2)
        maxneg[i] = 0;                               // 0.0f  (max over negatives of sim+2)
    }
}

// ---- kernel 2: fused GEMM + masked row min/max, B direct-from-cache ----
// block = 256 thr = 4 waves; wave w owns rows [bx*256 + w*64, +64) (ms=4).
// Block sweeps 512 cols (by), 32 at a time (nt=2). No LDS, no barriers.
__global__ __launch_bounds__(256, 2) void triplet_main(const u16* __restrict__ Ebf,
                                                       const int* __restrict__ labels,
                                                       int* __restrict__ minpos,
                                                       int* __restrict__ maxneg) {
    const int tid  = threadIdx.x;
    const int w    = tid >> 6;
    const int l    = tid & 63;
    const int quad = l >> 4;
    const int r16  = l & 15;

    const int mblk  = blockIdx.x * 256 + w * 64;     // wave's first row
    const int nbase = blockIdx.y * 512;

    // Preload A fragments: a[ms][k] covers rows [mblk+ms*16,+16), k-chunk [k*32,+32)
    bf16x8 a[4][8];
#pragma unroll
    for (int ms = 0; ms < 4; ++ms) {
        const u16* ap = Ebf + (size_t)(mblk + ms * 16 + r16) * DDIM + quad * 8;
#pragma unroll
        for (int k = 0; k < 8; ++k) a[ms][k] = ld_frag(ap + k * 32);
    }

    int lab_row[4][4];
#pragma unroll
    for (int ms = 0; ms < 4; ++ms)
#pragma unroll
        for (int r = 0; r < 4; ++r)
            lab_row[ms][r] = labels[mblk + ms * 16 + quad * 4 + r];

    float minp[4][4], maxn[4][4];
#pragma unroll
    for (int ms = 0; ms < 4; ++ms)
#pragma unroll
        for (int r = 0; r < 4; ++r) { minp[ms][r] = __builtin_inff(); maxn[ms][r] = -__builtin_inff(); }

    // B fragment pointers for this lane: col nt*16+r16 of the current 32-col tile
    const u16* bp0 = Ebf + (size_t)(nbase + r16) * DDIM + quad * 8;
    const u16* bp1 = bp0 + 16 * DDIM;

    // prime the k-pipeline with (tile 0, k=0)
    bf16x8 b0[2];
    b0[0] = ld_frag(bp0);
    b0[1] = ld_frag(bp1);

#pragma unroll 1
    for (int nn = 0; nn < 16; ++nn) {
        const int n0 = nbase + nn * 32;

        int lab_c[2];                                // used only in fold -> latency hidden
        lab_c[0] = labels[n0 + r16];
        lab_c[1] = labels[n0 + 16 + r16];

        f32x4 acc[4][2];
#pragma unroll
        for (int ms = 0; ms < 4; ++ms)
#pragma unroll
            for (int nt = 0; nt < 2; ++nt)
                acc[ms][nt] = (f32x4){0.f, 0.f, 0.f, 0.f};

        // advance for next tile; 0 on the last (k=7 prefetch re-reads k=0: harmless L1 hit)
        const int nstep = (nn < 15) ? 32 * DDIM : 0;

        __builtin_amdgcn_s_setprio(1);
#pragma unroll
        for (int k = 0; k < 8; ++k) {
            bf16x8 b1[2];
            const int off = (k < 7) ? (k + 1) * 32 : nstep;  // k=7: prefetch next tile's k=0
            b1[0] = ld_frag(bp0 + off);
            b1[1] = ld_frag(bp1 + off);
#pragma unroll
            for (int ms = 0; ms < 4; ++ms)
#pragma unroll
                for (int nt = 0; nt < 2; ++nt)
                    acc[ms][nt] = __builtin_amdgcn_mfma_f32_16x16x32_bf16(
                        a[ms][k], b0[nt], acc[ms][nt], 0, 0, 0);
            b0[0] = b1[0];
            b0[1] = b1[1];
        }
        __builtin_amdgcn_s_setprio(0);

        bp0 += nstep;
        bp1 += nstep;

        // masked fold. Exact diag handling only where col range may hit row range.
        const bool diagTile = (n0 < mblk + 64) && (mblk < n0 + 32);
        if (__builtin_expect(diagTile, 0)) {
#pragma unroll
            for (int nt = 0; nt < 2; ++nt) {
                const int colg = n0 + nt * 16 + r16;
#pragma unroll
                for (int ms = 0; ms < 4; ++ms)
#pragma unroll
                    for (int r = 0; r < 4; ++r) {
                        const int rowg = mblk + ms * 16 + quad * 4 + r;
                        const float s = acc[ms][nt][r];
                        const bool same = (lab_c[nt] == lab_row[ms][r]);
                        const bool pos  = same && (colg != rowg);
                        minp[ms][r] = fminf(minp[ms][r], pos  ?  s : __builtin_inff());
                        maxn[ms][r] = fmaxf(maxn[ms][r], same ? -__builtin_inff() : s);
                    }
            }
        } else {
#pragma unroll
            for (int nt = 0; nt < 2; ++nt)
#pragma unroll
                for (int ms = 0; ms < 4; ++ms)
#pragma unroll
                    for (int r = 0; r < 4; ++r) {
                        const float s = acc[ms][nt][r];
                        const bool same = (lab_c[nt] == lab_row[ms][r]);
                        minp[ms][r] = fminf(minp[ms][r], same ?  s : __builtin_inff());
                        maxn[ms][r] = fmaxf(maxn[ms][r], same ? -__builtin_inff() : s);
                    }
        }
    }

    // reduce across the 16 lanes sharing a quad (same rows, different cols)
#pragma unroll
    for (int mask = 1; mask <= 8; mask <<= 1) {
#pragma unroll
        for (int ms = 0; ms < 4; ++ms)
#pragma unroll
            for (int r = 0; r < 4; ++r) {
                minp[ms][r] = fminf(minp[ms][r], __shfl_xor(minp[ms][r], mask, 64));
                maxn[ms][r] = fmaxf(maxn[ms][r], __shfl_xor(maxn[ms][r], mask, 64));
            }
    }
    if (r16 == 0) {
#pragma unroll
        for (int ms = 0; ms < 4; ++ms)
#pragma unroll
            for (int r = 0; r < 4; ++r) {
                const int rowg = mblk + ms * 16 + quad * 4 + r;
                atomicMin(minpos + rowg, __float_as_int(minp[ms][r] + 2.0f));
                atomicMax(maxneg + rowg, __float_as_int(maxn[ms][r] + 2.0f));
            }
    }
}

// ---- kernel 3: finalize (single block, 1024 threads) ----
__global__ __launch_bounds__(1024) void finalize_kernel(const int* __restrict__ minpos,
                                                        const int* __restrict__ maxneg,
                                                        float* __restrict__ out) {
    __shared__ float ssum[16], scnt[16];
    float sum = 0.f, cnt = 0.f;
#pragma unroll
    for (int it = 0; it < 8; ++it) {
        const int i = it * 1024 + threadIdx.x;
        const float mp = __int_as_float(minpos[i]);  // min(sim)+2 over positives; +inf if none
        const float mn = __int_as_float(maxneg[i]);  // max(sim)+2 over negatives; 0 if none
        if (mp < 1e30f && mn > 0.5f) {
            // dist = sqrt(2 - 2*sim), sim = stored - 2  =>  2 - 2*(stored-2) = 6 - 2*stored
            const float dap = sqrtf(fmaxf(6.0f - 2.0f * mp, 0.0f) + 1e-12f);
            const float dan = sqrtf(fmaxf(6.0f - 2.0f * mn, 0.0f) + 1e-12f);
            sum += fmaxf(dap - dan + 0.3f, 0.0f);
            cnt += 1.0f;
        }
    }
#pragma unroll
    for (int off = 32; off > 0; off >>= 1) {
        sum += __shfl_down(sum, off, 64);
        cnt += __shfl_down(cnt, off, 64);
    }
    const int wid = threadIdx.x >> 6;
    if ((threadIdx.x & 63) == 0) { ssum[wid] = sum; scnt[wid] = cnt; }
    __syncthreads();
    if (threadIdx.x == 0) {
        float S = 0.f, C = 0.f;
#pragma unroll
        for (int i = 0; i < 16; ++i) { S += ssum[i]; C += scnt[i]; }
        out[0] = (C > 0.f) ? (S / C) : 0.f;
    }
}

extern "C" void kernel_launch(void* const* d_in, const int* in_sizes, int n_in,
                              void* d_out, int out_size, void* d_ws, size_t ws_size,
                              hipStream_t stream) {
    const float* emb    = (const float*)d_in[0];
    const int*   labels = (const int*)d_in[1];
    float*       out    = (float*)d_out;

    u16* Ebf    = (u16*)d_ws;                                  // 4 MB
    int* minpos = (int*)((char*)d_ws + (size_t)BDIM * DDIM * 2);
    int* maxneg = minpos + BDIM;

    cvt_init_kernel<<<dim3((BDIM * DDIM / 4) / 256), dim3(256), 0, stream>>>(emb, Ebf, minpos, maxneg);
    triplet_main<<<dim3(BDIM / 256, BDIM / 512), dim3(256), 0, stream>>>(Ebf, labels, minpos, maxneg);
    finalize_kernel<<<dim3(1), dim3(1024), 0, stream>>>(minpos, maxneg, out);
}

// Round 6
// 115.885 us; speedup vs baseline: 1.1606x; 1.1606x over previous
//
#include <hip/hip_runtime.h>
#include <hip/hip_bf16.h>

// TripletLoss: fused E·E^T + masked row min/max reduction. B=8192, D=256.
// dist = sqrt(2-2*sim) monotone decreasing in sim =>
//   dist_ap = dist(min sim over positives), dist_an = dist(max sim over negatives).
//
// R10: BARRIER-FREE WAVE-PRIVATE PIPELINES. Evidence: R5 (lockstep, LDS) = 47us,
// MfmaUtil ~= VALUBusy ~= 27%, sum 54% -> waves phase-locked by the per-iteration
// __syncthreads (matrix pipe idles during block-wide fold and vice versa). R9
// (free-run, no LDS) = 75us -> latency-bound at depth-1 reg prefetch. R10 keeps
// LDS staging + full-tile-ahead prefetch (latency covered) but makes each wave's
// pipeline PRIVATE: per-wave 2 x 8KB buffers, 16-col tiles (nt=1), per-wave counted
// s_waitcnt vmcnt(8), ZERO s_barrier in the loop. Waves de-phase; fold(VALU) of one
// wave overlaps MFMA of another. Buffer reuse is safe without barriers: a wave's
// ds_reads of a buffer complete before the consuming MFMAs issue (compiler lgkm),
// i.e. before the wave overwrites that buffer two tiles later.

#define BDIM 8192
#define DDIM 256

typedef short bf16x8 __attribute__((ext_vector_type(8)));
typedef float f32x4  __attribute__((ext_vector_type(4)));
typedef unsigned short u16;

static __device__ __forceinline__ bf16x8 ld_frag(const u16* p) {
    return *reinterpret_cast<const bf16x8*>(p);
}

static __device__ __forceinline__ u16 f2bf(float f) {
    union { float f; unsigned int u; } x; x.f = f;
    unsigned int u = x.u;
    unsigned int r = u + 0x7fffu + ((u >> 16) & 1u);  // RNE
    return (u16)(r >> 16);
}

static __device__ __forceinline__ void gload_lds16(const u16* g, u16* l) {
    __builtin_amdgcn_global_load_lds(
        (const __attribute__((address_space(1))) unsigned int*)g,
        (__attribute__((address_space(3))) unsigned int*)l, 16, 0, 0);
}

// ---- kernel 1: fp32 -> bf16 convert + init reduction arrays ----
__global__ __launch_bounds__(256) void cvt_init_kernel(const float* __restrict__ in,
                                                       u16* __restrict__ out,
                                                       int* __restrict__ minpos,
                                                       int* __restrict__ maxneg) {
    int i = blockIdx.x * 256 + threadIdx.x;          // 524288 threads, 4 elems each
    const float4 v = reinterpret_cast<const float4*>(in)[i];
    ushort4 o;
    o.x = f2bf(v.x); o.y = f2bf(v.y); o.z = f2bf(v.z); o.w = f2bf(v.w);
    reinterpret_cast<ushort4*>(out)[i] = o;
    if (i < BDIM) {
        minpos[i] = 0x7f800000;                      // +inf  (min over positives of sim+2)
        maxneg[i] = 0;                               // 0.0f  (max over negatives of sim+2)
    }
}

// ---- kernel 2: fused GEMM + masked row min/max, wave-private pipelines ----
// block = 256 thr = 4 waves; wave w owns rows [bx*256 + w*64, +64) (ms=4).
// Each wave sweeps the block's 512-col panel in 16-col tiles (nt=1, 32 tiles),
// staged into its PRIVATE 2 x 8KB LDS double-buffer with 8 gload_lds per tile;
// swizzle chunk c of row r at position c^(r&7) applied on the GLOBAL source.
__global__ __launch_bounds__(256, 2) void triplet_main(const u16* __restrict__ Ebf,
                                                       const int* __restrict__ labels,
                                                       int* __restrict__ minpos,
                                                       int* __restrict__ maxneg) {
    __shared__ __align__(16) u16 smem[4][2][16 * DDIM];  // per-wave double buffer, 64KB
    __shared__ int slab[512];                            // block's column labels

    const int tid  = threadIdx.x;
    const int w    = tid >> 6;
    const int l    = tid & 63;
    const int quad = l >> 4;
    const int r16  = l & 15;

    const int mblk  = blockIdx.x * 256 + w * 64;     // wave's first row
    const int nbase = blockIdx.y * 512;

    // column labels for the block's 512-col panel
    slab[tid]       = labels[nbase + tid];
    slab[256 + tid] = labels[nbase + 256 + tid];

    // Preload A fragments: a[ms][k] covers rows [mblk+ms*16,+16), k-chunk [k*32,+32)
    bf16x8 a[4][8];
#pragma unroll
    for (int ms = 0; ms < 4; ++ms) {
        const u16* ap = Ebf + (size_t)(mblk + ms * 16 + r16) * DDIM + quad * 8;
#pragma unroll
        for (int k = 0; k < 8; ++k) a[ms][k] = ld_frag(ap + k * 32);
    }

    int lab_row[4][4];
#pragma unroll
    for (int ms = 0; ms < 4; ++ms)
#pragma unroll
        for (int r = 0; r < 4; ++r)
            lab_row[ms][r] = labels[mblk + ms * 16 + quad * 4 + r];

    float minp[4][4], maxn[4][4];
#pragma unroll
    for (int ms = 0; ms < 4; ++ms)
#pragma unroll
        for (int r = 0; r < 4; ++r) { minp[ms][r] = __builtin_inff(); maxn[ms][r] = -__builtin_inff(); }

    __syncthreads();                                 // slab ready (only barrier in kernel)

    // swizzled-read lane constants
    const int qs = quad ^ (r16 & 3);                 // low-2-bit chunk index after swizzle
    const int s4 = (r16 >> 2) & 1;                   // bit-2 of swizzle

    // stage 16-col tile t (16 rows x 512B = 8KB) into this wave's buffer buf.
    // 8 gload_lds x (64 lanes x 16B); lane l of chunk-id q=it*64+l covers row q>>5,
    // swizzled chunk position (q&31)^(row&7) taken from the global source.
    u16* const myLds = &smem[w][0][0];
    auto stage = [&](int t, int buf) {
        const int n1 = nbase + t * 16;
#pragma unroll
        for (int it = 0; it < 8; ++it) {
            const int q = it * 64 + l;               // 0..511
            const int r = q >> 5;                    // row 0..15
            const int c = (q & 31) ^ (r & 7);        // swizzled chunk
            gload_lds16(Ebf + ((size_t)(n1 + r) << 8) + c * 8,
                        myLds + buf * (16 * DDIM) + it * 512);
        }
    };

    stage(0, 0);                                     // prologue: prefetch tile 0

#pragma unroll 1
    for (int t = 0; t < 32; ++t) {
        const int cur = t & 1;

        // issue next tile's stage early (into the buffer last read at t-1, whose
        // ds_reads completed before t-1's MFMAs issued), then counted wait:
        // retire tile t's 8 loads, leave tile t+1's 8 in flight.
        if (t + 1 < 32) {
            stage(t + 1, cur ^ 1);
            asm volatile("s_waitcnt vmcnt(8)" ::: "memory");
        } else {
            asm volatile("s_waitcnt vmcnt(0)" ::: "memory");
        }
        __builtin_amdgcn_sched_barrier(0);           // no ds_read hoisting above the wait

        const int n0    = nbase + t * 16;
        const int lab_c = slab[t * 16 + r16];

        f32x4 acc[4];
#pragma unroll
        for (int ms = 0; ms < 4; ++ms) acc[ms] = (f32x4){0.f, 0.f, 0.f, 0.f};

        const u16* bp = myLds + cur * (16 * DDIM) + r16 * DDIM + qs * 8;

        __builtin_amdgcn_s_setprio(1);
#pragma unroll
        for (int k = 0; k < 8; ++k) {
            const bf16x8 b = ld_frag(bp + ((k ^ s4) << 5));
#pragma unroll
            for (int ms = 0; ms < 4; ++ms)
                acc[ms] = __builtin_amdgcn_mfma_f32_16x16x32_bf16(
                    a[ms][k], b, acc[ms], 0, 0, 0);
        }
        __builtin_amdgcn_s_setprio(0);

        // masked fold. Exact diag handling only where col range may hit row range.
        const bool diagTile = (n0 < mblk + 64) && (mblk < n0 + 16);
        if (__builtin_expect(diagTile, 0)) {
            const int colg = n0 + r16;
#pragma unroll
            for (int ms = 0; ms < 4; ++ms)
#pragma unroll
                for (int r = 0; r < 4; ++r) {
                    const int rowg = mblk + ms * 16 + quad * 4 + r;
                    const float s = acc[ms][r];
                    const bool same = (lab_c == lab_row[ms][r]);
                    const bool pos  = same && (colg != rowg);
                    minp[ms][r] = fminf(minp[ms][r], pos  ?  s : __builtin_inff());
                    maxn[ms][r] = fmaxf(maxn[ms][r], same ? -__builtin_inff() : s);
                }
        } else {
#pragma unroll
            for (int ms = 0; ms < 4; ++ms)
#pragma unroll
                for (int r = 0; r < 4; ++r) {
                    const float s = acc[ms][r];
                    const bool same = (lab_c == lab_row[ms][r]);
                    minp[ms][r] = fminf(minp[ms][r], same ?  s : __builtin_inff());
                    maxn[ms][r] = fmaxf(maxn[ms][r], same ? -__builtin_inff() : s);
                }
        }
    }

    // reduce across the 16 lanes sharing a quad (same rows, different cols)
#pragma unroll
    for (int mask = 1; mask <= 8; mask <<= 1) {
#pragma unroll
        for (int ms = 0; ms < 4; ++ms)
#pragma unroll
            for (int r = 0; r < 4; ++r) {
                minp[ms][r] = fminf(minp[ms][r], __shfl_xor(minp[ms][r], mask, 64));
                maxn[ms][r] = fmaxf(maxn[ms][r], __shfl_xor(maxn[ms][r], mask, 64));
            }
    }
    if (r16 == 0) {
#pragma unroll
        for (int ms = 0; ms < 4; ++ms)
#pragma unroll
            for (int r = 0; r < 4; ++r) {
                const int rowg = mblk + ms * 16 + quad * 4 + r;
                atomicMin(minpos + rowg, __float_as_int(minp[ms][r] + 2.0f));
                atomicMax(maxneg + rowg, __float_as_int(maxn[ms][r] + 2.0f));
            }
    }
}

// ---- kernel 3: finalize (single block, 1024 threads) ----
__global__ __launch_bounds__(1024) void finalize_kernel(const int* __restrict__ minpos,
                                                        const int* __restrict__ maxneg,
                                                        float* __restrict__ out) {
    __shared__ float ssum[16], scnt[16];
    float sum = 0.f, cnt = 0.f;
#pragma unroll
    for (int it = 0; it < 8; ++it) {
        const int i = it * 1024 + threadIdx.x;
        const float mp = __int_as_float(minpos[i]);  // min(sim)+2 over positives; +inf if none
        const float mn = __int_as_float(maxneg[i]);  // max(sim)+2 over negatives; 0 if none
        if (mp < 1e30f && mn > 0.5f) {
            // dist = sqrt(2 - 2*sim), sim = stored - 2  =>  2 - 2*(stored-2) = 6 - 2*stored
            const float dap = sqrtf(fmaxf(6.0f - 2.0f * mp, 0.0f) + 1e-12f);
            const float dan = sqrtf(fmaxf(6.0f - 2.0f * mn, 0.0f) + 1e-12f);
            sum += fmaxf(dap - dan + 0.3f, 0.0f);
            cnt += 1.0f;
        }
    }
#pragma unroll
    for (int off = 32; off > 0; off >>= 1) {
        sum += __shfl_down(sum, off, 64);
        cnt += __shfl_down(cnt, off, 64);
    }
    const int wid = threadIdx.x >> 6;
    if ((threadIdx.x & 63) == 0) { ssum[wid] = sum; scnt[wid] = cnt; }
    __syncthreads();
    if (threadIdx.x == 0) {
        float S = 0.f, C = 0.f;
#pragma unroll
        for (int i = 0; i < 16; ++i) { S += ssum[i]; C += scnt[i]; }
        out[0] = (C > 0.f) ? (S / C) : 0.f;
    }
}

extern "C" void kernel_launch(void* const* d_in, const int* in_sizes, int n_in,
                              void* d_out, int out_size, void* d_ws, size_t ws_size,
                              hipStream_t stream) {
    const float* emb    = (const float*)d_in[0];
    const int*   labels = (const int*)d_in[1];
    float*       out    = (float*)d_out;

    u16* Ebf    = (u16*)d_ws;                                  // 4 MB
    int* minpos = (int*)((char*)d_ws + (size_t)BDIM * DDIM * 2);
    int* maxneg = minpos + BDIM;

    cvt_init_kernel<<<dim3((BDIM * DDIM / 4) / 256), dim3(256), 0, stream>>>(emb, Ebf, minpos, maxneg);
    triplet_main<<<dim3(BDIM / 256, BDIM / 512), dim3(256), 0, stream>>>(Ebf, labels, minpos, maxneg);
    finalize_kernel<<<dim3(1), dim3(1024), 0, stream>>>(minpos, maxneg, out);
}